// Round 6
// baseline (252.553 us; speedup 1.0000x reference)
//
#include <hip/hip_runtime.h>

// Problem constants (VectorQuantizer: B=16, D=64, H=64, W=64, K=1024)
#define DD 64
#define KK 1024
#define NPTS 65536      // B*H*W
#define TOTAL 4194304   // B*D*H*W

// Output layout (concatenated flat, all read as float32 by harness)
#define OFF_L1 4194304
#define OFF_L2 4194305
#define OFF_IDX 4194306

#define NT 128           // points per block
#define KT 128           // codes per k-tile (grouping only; e comes from global)
#define NBLK (NPTS / NT) // 512

// ---------------- fused argmin + quantize + loss, single kernel ----------------
// 256 threads/block, tile 128 points x full K. Micro-tile 8x8.
// x in LDS (2 conflict-free ds_read_b128 per d = 24 cy/wave on the shared LDS
// pipe, < 32 cy/wave VALU) ; e read straight from global — 16-way broadcast,
// 4 distinct 64B addresses per wave per load -> L1/L2 broadcast on the VMEM
// pipe. No barriers in the k-loop. e-norms accumulated in-loop (replaces the
// enorm kernel). Epilogue: gather chosen codes (L2-hot scatter), re-read x
// coalesced, block-reduced loss, ticket-based finalize.
__global__ __launch_bounds__(256) void vq_mega(const float* __restrict__ x,
                                               const float* __restrict__ e,
                                               float* __restrict__ out,
                                               float* __restrict__ sum,
                                               unsigned* __restrict__ cnt) {
    __shared__ __align__(16) float xs[DD * NT];   // 32 KB; reused for argmin reduce
    __shared__ int ks[NT];
    __shared__ float red[4];

    const int tid = threadIdx.x;
    const int tn4 = (tid & 15) * 4;   // point group A base; group B = 64 + tn4
    const int tk = tid >> 4;          // 0..15
    const int tk4 = tk * 4;           // code group A base; group B = 64 + tk4

    const int n0 = blockIdx.x * NT;
    const int b = n0 >> 12;
    const int hw0 = n0 & 4095;

    // ---- stage x tile: xs[d][p], contiguous 512B per 32 lanes ----
    {
        const int sd = tid >> 5;          // 0..7
        const int sc = (tid & 31) * 4;    // 0..124
#pragma unroll
        for (int r = 0; r < 8; ++r) {
            const int d = r * 8 + sd;
            *(float4*)(&xs[d * NT + sc]) =
                *(const float4*)(x + ((b * DD + d) << 12) + hw0 + sc);
        }
    }
    __syncthreads();

    float bv[8];
    int bi[8];
#pragma unroll
    for (int i = 0; i < 8; ++i) { bv[i] = 3.4e38f; bi[i] = 0; }

    for (int kt = 0; kt < KK / KT; ++kt) {
        const int k0 = kt * KT;
        const float* eA = e + k0 + tk4;        // + d*KK per step
        const float* eB = e + k0 + 64 + tk4;

        float acc[8][8];
        float en[8];
#pragma unroll
        for (int i = 0; i < 8; ++i) {
            en[i] = 0.f;
#pragma unroll
            for (int j = 0; j < 8; ++j) acc[i][j] = 0.f;
        }

#pragma unroll 4
        for (int d = 0; d < DD; ++d) {
            const float4 e0 = *(const float4*)(eA + d * KK);   // VMEM, broadcast
            const float4 e1 = *(const float4*)(eB + d * KK);
            const float4 x0 = *(const float4*)(&xs[d * NT + tn4]);        // LDS
            const float4 x1 = *(const float4*)(&xs[d * NT + 64 + tn4]);   // LDS
            const float xa[8] = {x0.x, x0.y, x0.z, x0.w, x1.x, x1.y, x1.z, x1.w};
            const float ee[8] = {e0.x, e0.y, e0.z, e0.w, e1.x, e1.y, e1.z, e1.w};
#pragma unroll
            for (int j = 0; j < 8; ++j) en[j] = fmaf(ee[j], ee[j], en[j]);
#pragma unroll
            for (int i = 0; i < 8; ++i)
#pragma unroll
                for (int j = 0; j < 8; ++j)
                    acc[i][j] = fmaf(xa[i], ee[j], acc[i][j]);
        }

        // dist = ||e||^2 - 2*dot ; ||x||^2 constant per point, dropped.
#pragma unroll
        for (int i = 0; i < 8; ++i) {
#pragma unroll
            for (int j = 0; j < 8; ++j) {
                const float dist = fmaf(-2.f, acc[i][j], en[j]);
                const int kj = (j < 4) ? (k0 + tk4 + j) : (k0 + 64 + tk4 + j - 4);
                // strict <: per-thread candidates ascend in k across j and kt
                if (dist < bv[i]) { bv[i] = dist; bi[i] = kj; }
            }
        }
    }

    // ---- cross-thread argmin reduce (16 tk-partials per point) ----
    __syncthreads();                 // all waves done reading xs
    float* rv = xs;                  // [pt][tk] stride 17
    float* ri = xs + NT * 17;        // 2176 + 2176 <= 8192 floats
#pragma unroll
    for (int i = 0; i < 8; ++i) {
        const int p = (i < 4) ? (tn4 + i) : (64 + tn4 + i - 4);
        rv[p * 17 + tk] = bv[i];
        ri[p * 17 + tk] = (float)bi[i];
    }
    __syncthreads();
    if (tid < NT) {
        float best = rv[tid * 17];
        float bidx = ri[tid * 17];
#pragma unroll
        for (int t = 1; t < 16; ++t) {
            const float v = rv[tid * 17 + t];
            const float id = ri[tid * 17 + t];
            if (v < best || (v == best && id < bidx)) { best = v; bidx = id; }
        }
        ks[tid] = (int)bidx;
        out[OFF_IDX + n0 + tid] = bidx;
    }
    __syncthreads();

    // ---- fused quantize + loss: thread = (point, d-half) ----
    const int p = tid & 127;
    const int dh = tid >> 7;         // 0 or 1
    const int kp = ks[p];
    const float* ecol = e + kp;      // e[d*KK + kp], L2-hot scatter
    float lacc = 0.f;
#pragma unroll 4
    for (int dd = 0; dd < 32; ++dd) {
        const int d = dh * 32 + dd;
        const float q = ecol[d * KK];
        const float xv = x[((b * DD + d) << 12) + hw0 + p];   // coalesced re-read
        out[((b * DD + d) << 12) + hw0 + p] = q;
        const float df = xv - q;
        lacc = fmaf(df, df, lacc);
    }

#pragma unroll
    for (int off = 32; off > 0; off >>= 1) lacc += __shfl_down(lacc, off, 64);
    if ((tid & 63) == 0) red[tid >> 6] = lacc;
    __syncthreads();
    if (tid == 0) {
        atomicAdd(sum, red[0] + red[1] + red[2] + red[3]);
        __threadfence();
        const unsigned old = atomicAdd(cnt, 1u);
        if (old == (NBLK - 1)) {            // last block: all sums visible
            const float s = atomicAdd(sum, 0.0f);
            const float m = s * (1.0f / (float)TOTAL);
            out[OFF_L1] = m;   // dictionary_loss
            out[OFF_L2] = m;   // commitment_loss (numerically identical)
        }
    }
}

extern "C" void kernel_launch(void* const* d_in, const int* in_sizes, int n_in,
                              void* d_out, int out_size, void* d_ws, size_t ws_size,
                              hipStream_t stream) {
    const float* x = (const float*)d_in[0];      // [16,64,64,64]
    const float* e = (const float*)d_in[1];      // [64,1024]
    float* out = (float*)d_out;

    float* sum = (float*)d_ws;                   // [0]
    unsigned* cnt = (unsigned*)d_ws + 1;         // [1]

    hipMemsetAsync(d_ws, 0, 8, stream);          // sum + ticket
    vq_mega<<<NBLK, 256, 0, stream>>>(x, e, out, sum, cnt);
}

// Round 7
// 189.856 us; speedup vs baseline: 1.3302x; 1.3302x over previous
//
#include <hip/hip_runtime.h>

// Problem constants (VectorQuantizer: B=16, D=64, H=64, W=64, K=1024)
#define DD 64
#define KK 1024
#define NPTS 65536      // B*H*W
#define TOTAL 4194304   // B*D*H*W

// Output layout (concatenated flat, all read as float32 by harness)
#define OFF_L1 4194304
#define OFF_L2 4194305
#define OFF_IDX 4194306

#define WS_ENORM 64      // ws float offset of enorm[1024]

#define NT 128           // points per block
#define KT 128           // codes per k-tile
#define NBLK (NPTS / NT) // 512

// ---------------- kernel 1: codebook squared norms (wide, ILP-deep) ----------------
// 16 blocks x 256 threads; block handles 64 codes, thread = (code, d-quarter).
// Per-wave loads are 256B coalesced, 16 independent loads in flight.
__global__ __launch_bounds__(256) void enorm_kernel(const float* __restrict__ e,
                                                    float* __restrict__ enorm) {
    __shared__ float red[64 * 4];
    const int tid = threadIdx.x;
    const int c = tid & 63;           // code within block
    const int q = tid >> 6;           // d-quarter 0..3
    const int k = blockIdx.x * 64 + c;
    float s = 0.f;
#pragma unroll
    for (int r = 0; r < 16; ++r) {
        const float v = e[(q * 16 + r) * KK + k];
        s = fmaf(v, v, s);
    }
    red[c * 4 + q] = s;
    __syncthreads();
    if (tid < 64) {
        enorm[blockIdx.x * 64 + tid] =
            red[tid * 4] + red[tid * 4 + 1] + red[tid * 4 + 2] + red[tid * 4 + 3];
    }
}

// ---------------- kernel 2: fused argmin + quantize + loss ----------------
// 256 threads/block, tile 128 points x 128 codes per k-tile (8 tiles).
// Micro-tile 8x8, BOTH operands split in two 4-element groups at {base, 64+base}
// so every ds_read_b128 is 256B-contiguous per 16 lanes (2-way alias = free).
// Model: per d-iter per wave 4 b128 = 48 cy on shared LDS pipe; 8 waves/CU ->
// 384 cy vs 256 VALU cy -> LDS-bound, VALUBusy ~67% expected.
__global__ __launch_bounds__(256) void vq_mega(const float* __restrict__ x,
                                               const float* __restrict__ e,
                                               const float* __restrict__ enorm,
                                               float* __restrict__ out,
                                               float* __restrict__ sum,
                                               unsigned* __restrict__ cnt) {
    __shared__ __align__(16) float xs[DD * NT];   // 32 KB  [d][pt]; live to epilogue
    __shared__ __align__(16) float es[DD * KT];   // 32 KB  [d][kk]; reused for reduce
    __shared__ int ks[NT];
    __shared__ float red[4];

    const int tid = threadIdx.x;
    const int tn4 = (tid & 15) * 4;   // point groups {tn4, 64+tn4}
    const int tk = tid >> 4;          // 0..15
    const int tk4 = tk * 4;           // code groups {tk4, 64+tk4}

    const int n0 = blockIdx.x * NT;
    const int b = n0 >> 12;
    const int hw0 = n0 & 4095;

    // staging decomposition: contiguous 512B per 32 lanes (conflict-free)
    const int sd = tid >> 5;          // 0..7
    const int sc = (tid & 31) * 4;    // 0..124

    // ---- stage x tile: xs[d][p] ----
#pragma unroll
    for (int r = 0; r < 8; ++r) {
        const int d = r * 8 + sd;
        *(float4*)(&xs[d * NT + sc]) =
            *(const float4*)(x + ((b * DD + d) << 12) + hw0 + sc);
    }

    float bv[8];
    int bi[8];
#pragma unroll
    for (int i = 0; i < 8; ++i) { bv[i] = 3.4e38f; bi[i] = 0; }

    for (int kt = 0; kt < KK / KT; ++kt) {
        const int k0 = kt * KT;

        __syncthreads();   // kt=0: x-stage visible; kt>0: prior tile's readers done
        // ---- stage e tile: es[d][kk] ----
#pragma unroll
        for (int r = 0; r < 8; ++r) {
            const int d = r * 8 + sd;
            *(float4*)(&es[d * KT + sc]) = *(const float4*)(e + d * KK + k0 + sc);
        }
        __syncthreads();

        const float4 enA = *(const float4*)(enorm + k0 + tk4);
        const float4 enB = *(const float4*)(enorm + k0 + 64 + tk4);

        float acc[8][8];
#pragma unroll
        for (int i = 0; i < 8; ++i)
#pragma unroll
            for (int j = 0; j < 8; ++j) acc[i][j] = 0.f;

#pragma unroll 8
        for (int d = 0; d < DD; ++d) {
            const float4 x0 = *(const float4*)(&xs[d * NT + tn4]);        // 2-way free
            const float4 x1 = *(const float4*)(&xs[d * NT + 64 + tn4]);
            const float4 e0 = *(const float4*)(&es[d * KT + tk4]);        // 2-way free
            const float4 e1 = *(const float4*)(&es[d * KT + 64 + tk4]);
            const float xa[8] = {x0.x, x0.y, x0.z, x0.w, x1.x, x1.y, x1.z, x1.w};
            const float ee[8] = {e0.x, e0.y, e0.z, e0.w, e1.x, e1.y, e1.z, e1.w};
#pragma unroll
            for (int i = 0; i < 8; ++i)
#pragma unroll
                for (int j = 0; j < 8; ++j)
                    acc[i][j] = fmaf(xa[i], ee[j], acc[i][j]);
        }

        const float en[8] = {enA.x, enA.y, enA.z, enA.w, enB.x, enB.y, enB.z, enB.w};
#pragma unroll
        for (int i = 0; i < 8; ++i) {
#pragma unroll
            for (int j = 0; j < 8; ++j) {
                const float dist = fmaf(-2.f, acc[i][j], en[j]);
                const int kj = (j < 4) ? (k0 + tk4 + j) : (k0 + 64 + tk4 + j - 4);
                // strict <: per-thread candidates ascend in k across j and kt
                if (dist < bv[i]) { bv[i] = dist; bi[i] = kj; }
            }
        }
    }

    // ---- cross-thread argmin reduce (16 tk-partials per point), in es ----
    __syncthreads();
    float* rv = es;                  // [pt][tk] stride 17
    float* ri = es + NT * 17;        // 2176 + 2176 <= 8192 floats
#pragma unroll
    for (int i = 0; i < 8; ++i) {
        const int p = (i < 4) ? (tn4 + i) : (64 + tn4 + i - 4);
        rv[p * 17 + tk] = bv[i];
        ri[p * 17 + tk] = (float)bi[i];
    }
    __syncthreads();
    if (tid < NT) {
        float best = rv[tid * 17];
        float bidx = ri[tid * 17];
#pragma unroll
        for (int t = 1; t < 16; ++t) {
            const float v = rv[tid * 17 + t];
            const float id = ri[tid * 17 + t];
            if (v < best || (v == best && id < bidx)) { best = v; bidx = id; }
        }
        ks[tid] = (int)bidx;
        out[OFF_IDX + n0 + tid] = bidx;
    }
    __syncthreads();

    // ---- fused quantize + loss: thread = (point, d-half); xs still valid ----
    const int p = tid & 127;
    const int dh = tid >> 7;         // 0 or 1
    const int kp = ks[p];
    const float* ecol = e + kp;      // e[d*KK + kp], L2-hot scatter
    float lacc = 0.f;
#pragma unroll 8
    for (int dd = 0; dd < 32; ++dd) {
        const int d = dh * 32 + dd;
        const float q = ecol[d * KK];
        const float xv = xs[d * NT + p];
        out[((b * DD + d) << 12) + hw0 + p] = q;
        const float df = xv - q;
        lacc = fmaf(df, df, lacc);
    }

#pragma unroll
    for (int off = 32; off > 0; off >>= 1) lacc += __shfl_down(lacc, off, 64);
    if ((tid & 63) == 0) red[tid >> 6] = lacc;
    __syncthreads();
    if (tid == 0) {
        atomicAdd(sum, red[0] + red[1] + red[2] + red[3]);
        __threadfence();
        const unsigned old = atomicAdd(cnt, 1u);
        if (old == (NBLK - 1)) {            // last block: all sums visible
            const float s = atomicAdd(sum, 0.0f);
            const float m = s * (1.0f / (float)TOTAL);
            out[OFF_L1] = m;   // dictionary_loss
            out[OFF_L2] = m;   // commitment_loss (numerically identical)
        }
    }
}

extern "C" void kernel_launch(void* const* d_in, const int* in_sizes, int n_in,
                              void* d_out, int out_size, void* d_ws, size_t ws_size,
                              hipStream_t stream) {
    const float* x = (const float*)d_in[0];      // [16,64,64,64]
    const float* e = (const float*)d_in[1];      // [64,1024]
    float* out = (float*)d_out;

    float* wsf = (float*)d_ws;
    float* sum = wsf;                            // [0]
    unsigned* cnt = (unsigned*)d_ws + 1;         // [1]
    float* enorm = wsf + WS_ENORM;

    hipMemsetAsync(d_ws, 0, 8, stream);          // sum + ticket
    enorm_kernel<<<16, 256, 0, stream>>>(e, enorm);
    vq_mega<<<NBLK, 256, 0, stream>>>(x, e, enorm, out, sum, cnt);
}